// Round 3
// baseline (409.185 us; speedup 1.0000x reference)
//
#include <hip/hip_runtime.h>

typedef __attribute__((ext_vector_type(4))) float f32x4;
typedef __attribute__((ext_vector_type(8))) __bf16 bf16x8;
typedef __attribute__((ext_vector_type(4))) __bf16 bf16x4;

#define LOG_2PI 1.8378770664093453f

__device__ __forceinline__ float softplus_f(float x) {
  return fmaxf(x, 0.f) + log1pf(expf(-fabsf(x)));
}

// ---------------- prep: marks_proj (blocks 0..1023) + zero accs (block 1024)
__global__ void prep_kernel(const float* __restrict__ em,
                            const float* __restrict__ Wp,
                            const float* __restrict__ bp,
                            float* __restrict__ mp,
                            float* __restrict__ accs) {
  const int b = blockIdx.x;
  if (b == 1024) {
    if (threadIdx.x < 8) accs[threadIdx.x] = 0.f;
    return;
  }
  const int d = threadIdx.x;
  float s = bp[d];
  const float* emr = em + b * 128;
#pragma unroll 4
  for (int k = 0; k < 128; ++k) s += emr[k] * Wp[k * 128 + d];
  mp[b * 128 + d] = s;
}

// ---------------- fused intensity (traj blocks 0..1023, events 1024..1151) --
// Swapped MFMA: D[m=hidden][n=row]; per-lane in-register hidden reduction.
// 16 tiles of 32 rows per block; depth-2 register prefetch; 1 barrier/tile;
// deferred serial softplus via double-buffered s_part.
__global__ __launch_bounds__(512, 4) void intensity2_kernel(
    const float* __restrict__ z_traj, const float* __restrict__ z_ev,
    const float* __restrict__ W1, const float* __restrict__ b1,
    const float* __restrict__ W2, const float* __restrict__ b2,
    const float* __restrict__ base_i, const float* __restrict__ times,
    float* __restrict__ accs) {
  __shared__ __align__(16) __bf16 zbuf[2][32 * 128];  // 16 KB
  __shared__ float s_part[2][32][9];                  // padded: conflict-free
  __shared__ float red[8];
  __shared__ __align__(16) float b1L[512];
  __shared__ __align__(16) float w2L[512];

  const int tid = threadIdx.x;
  const int wid = tid >> 6, lid = tid & 63;
  const int g = lid >> 4, q = lid & 15;
  const int cb = wid * 64;

  const int b = blockIdx.x;
  const bool traj = (b < 1024);
  const float* z = traj ? z_traj : z_ev;
  const int tile0 = (traj ? b : (b - 1024)) * 16;

  b1L[tid] = b1[tid];
  w2L[tid] = W2[tid];

  // W1 A-frags: frag[cf][kf] elem j = W1[kf*32+g*8+j][cb+cf*16+q]
  bf16x8 bw[4][4];
#pragma unroll
  for (int cf = 0; cf < 4; ++cf) {
    const int col = cb + cf * 16 + q;
#pragma unroll
    for (int kf = 0; kf < 4; ++kf) {
      bf16x8 f;
#pragma unroll
      for (int j = 0; j < 8; ++j) f[j] = (__bf16)W1[(kf * 32 + g * 8 + j) * 512 + col];
      bw[cf][kf] = f;
    }
  }
  const float sbias = b2[0] + base_i[0];

  const int srow = tid >> 4, sk8 = (tid & 15) * 8;
  const int stg_byte = ((srow * 256 + sk8 * 2) ^ ((srow & 7) << 4));

  float local = 0.f, kls = 0.f;

  // prologue: stage tile0 directly; issue loads for tile1 (rA), tile2 (rB)
  {
    const float* p = z + (size_t)tile0 * 4096 + tid * 8;
    f32x4 r0 = *(const f32x4*)p, r1 = *(const f32x4*)(p + 4);
    if (traj) {
      kls += r0[0] * r0[0] + r0[1] * r0[1] + r0[2] * r0[2] + r0[3] * r0[3];
      kls += r1[0] * r1[0] + r1[1] * r1[1] + r1[2] * r1[2] + r1[3] * r1[3];
    }
    bf16x8 v;
#pragma unroll
    for (int j = 0; j < 4; ++j) { v[j] = (__bf16)r0[j]; v[4 + j] = (__bf16)r1[j]; }
    *(bf16x8*)((char*)zbuf[0] + stg_byte) = v;
  }
  f32x4 rA0, rA1, rB0, rB1;
  { const float* p = z + (size_t)(tile0 + 1) * 4096 + tid * 8; rA0 = *(const f32x4*)p; rA1 = *(const f32x4*)(p + 4); }
  { const float* p = z + (size_t)(tile0 + 2) * 4096 + tid * 8; rB0 = *(const f32x4*)p; rB1 = *(const f32x4*)(p + 4); }
  __syncthreads();

#define IBODY(T, ZC, RR0, RR1)                                                     \
  do {                                                                             \
    f32x4 acc[2][4] = {};                                                          \
    char* zc = (char*)zbuf[ZC];                                                    \
    _Pragma("unroll") for (int kf = 0; kf < 4; ++kf) {                             \
      _Pragma("unroll") for (int rf = 0; rf < 2; ++rf) {                           \
        const int row = rf * 16 + q;                                               \
        bf16x8 a = *(const bf16x8*)(zc + ((row * 256 + kf * 64 + g * 16) ^ ((row & 7) << 4))); \
        _Pragma("unroll") for (int cf = 0; cf < 4; ++cf)                           \
          acc[rf][cf] = __builtin_amdgcn_mfma_f32_16x16x32_bf16(bw[cf][kf], a, acc[rf][cf], 0, 0, 0); \
      }                                                                            \
    }                                                                              \
    /* convert staged regs (tile T+1) -> zbuf[ZC^1] */                             \
    if (traj) {                                                                    \
      kls += RR0[0] * RR0[0] + RR0[1] * RR0[1] + RR0[2] * RR0[2] + RR0[3] * RR0[3];\
      kls += RR1[0] * RR1[0] + RR1[1] * RR1[1] + RR1[2] * RR1[2] + RR1[3] * RR1[3];\
    }                                                                              \
    {                                                                              \
      bf16x8 v;                                                                    \
      _Pragma("unroll") for (int j = 0; j < 4; ++j) { v[j] = (__bf16)RR0[j]; v[4 + j] = (__bf16)RR1[j]; } \
      *(bf16x8*)((char*)zbuf[(ZC) ^ 1] + stg_byte) = v;                            \
    }                                                                              \
    /* re-issue loads for tile T+3 */                                              \
    {                                                                              \
      int tl = (T) + 3; if (tl > 15) tl = 15;                                      \
      const float* p = z + (size_t)(tile0 + tl) * 4096 + tid * 8;                  \
      RR0 = *(const f32x4*)p; RR1 = *(const f32x4*)(p + 4);                        \
    }                                                                              \
    /* epilogue: in-register hidden reduction + 2 shuffles */                      \
    _Pragma("unroll") for (int rf = 0; rf < 2; ++rf) {                             \
      float partial = 0.f;                                                         \
      _Pragma("unroll") for (int cf = 0; cf < 4; ++cf) {                           \
        const int c0 = cb + cf * 16 + g * 4;                                       \
        f32x4 bv = *(const f32x4*)&b1L[c0];                                        \
        f32x4 wv = *(const f32x4*)&w2L[c0];                                        \
        _Pragma("unroll") for (int i = 0; i < 4; ++i)                              \
          partial += fmaxf(acc[rf][cf][i] + bv[i], 0.f) * wv[i];                   \
      }                                                                            \
      partial += __shfl_xor(partial, 16);                                          \
      partial += __shfl_xor(partial, 32);                                          \
      if (lid < 16) s_part[(T) & 1][rf * 16 + lid][wid] = partial;                 \
    }                                                                              \
    /* deferred serial: finalize tile T-1 */                                       \
    if ((T) > 0 && tid < 32) {                                                     \
      float s = sbias;                                                             \
      _Pragma("unroll") for (int w = 0; w < 8; ++w) s += s_part[((T)&1) ^ 1][tid][w]; \
      const float lam = softplus_f(s);                                             \
      const int ta = tile0 + (T) - 1;                                              \
      if (traj) {                                                                  \
        const int ts = ta >> 1;                                                    \
        local += lam * (times[ts + 1] - times[ts]) * (1.f / 64.f);                 \
      } else {                                                                     \
        local += logf(lam + 1e-8f) * (1.f / 64.f);                                 \
      }                                                                            \
    }                                                                              \
    __syncthreads();                                                               \
  } while (0)

#pragma unroll 1
  for (int t = 0; t < 16; t += 2) {
    switch (t) {  // compile-time T for serial-skip folding; ZC parity fixed
      case 0:  IBODY(0, 0, rA0, rA1);  IBODY(1, 1, rB0, rB1);  break;
      case 2:  IBODY(2, 0, rA0, rA1);  IBODY(3, 1, rB0, rB1);  break;
      case 4:  IBODY(4, 0, rA0, rA1);  IBODY(5, 1, rB0, rB1);  break;
      case 6:  IBODY(6, 0, rA0, rA1);  IBODY(7, 1, rB0, rB1);  break;
      case 8:  IBODY(8, 0, rA0, rA1);  IBODY(9, 1, rB0, rB1);  break;
      case 10: IBODY(10, 0, rA0, rA1); IBODY(11, 1, rB0, rB1); break;
      case 12: IBODY(12, 0, rA0, rA1); IBODY(13, 1, rB0, rB1); break;
      default: IBODY(14, 0, rA0, rA1); IBODY(15, 1, rB0, rB1); break;
    }
  }
#undef IBODY

  // tail: finalize tile 15 (in s_part[1])
  if (tid < 32) {
    float s = sbias;
#pragma unroll
    for (int w = 0; w < 8; ++w) s += s_part[1][tid][w];
    const float lam = softplus_f(s);
    const int ta = tile0 + 15;
    if (traj) {
      const int ts = ta >> 1;
      local += lam * (times[ts + 1] - times[ts]) * (1.f / 64.f);
    } else {
      local += logf(lam + 1e-8f) * (1.f / 64.f);
    }
  }

  // block reductions + atomics (local lives on wave 0, lanes 0..31)
  if (wid == 0) {
#pragma unroll
    for (int m = 16; m >= 1; m >>= 1) local += __shfl_xor(local, m);
    if (lid == 0) atomicAdd(traj ? &accs[0] : &accs[1], local);
  }
  if (traj) {
#pragma unroll
    for (int m = 32; m >= 1; m >>= 1) kls += __shfl_xor(kls, m);
    if (lid == 0) red[wid] = kls;
    __syncthreads();
    if (tid == 0) {
      float s = 0.f;
      for (int w = 0; w < 8; ++w) s += red[w];
      atomicAdd(&accs[3], s);
    }
  }
}

// ---------------- decoder: swapped GEMM1 -> h (LDS) -> swapped GEMM2 -> logp
__global__ __launch_bounds__(512, 2) void decoder2_kernel(
    const float* __restrict__ z,
    const float* __restrict__ Wd1, const float* __restrict__ bd1,
    const float* __restrict__ Wd2, const float* __restrict__ bd2,
    const float* __restrict__ mp, float* __restrict__ recon_acc) {
  __shared__ __align__(16) __bf16 zbuf[2][32 * 128];  // 16 KB
  __shared__ __align__(16) __bf16 hbuf[32 * 512];     // 32 KB
  __shared__ float s_part[32][9];
  __shared__ float red[8];

  const int tid = threadIdx.x;
  const int wid = tid >> 6, lid = tid & 63;
  const int g = lid >> 4, q = lid & 15;
  const int cb = wid * 64;
  const int tile0 = blockIdx.x * 8;

  // Wd1 A-frags (same layout as intensity bw)
  bf16x8 bw1[4][4];
  f32x4 bd1v[4];
#pragma unroll
  for (int cf = 0; cf < 4; ++cf) {
    const int col = cb + cf * 16 + q;
#pragma unroll
    for (int i = 0; i < 4; ++i) bd1v[cf][i] = bd1[cb + cf * 16 + g * 4 + i];
#pragma unroll
    for (int kf = 0; kf < 4; ++kf) {
      bf16x8 f;
#pragma unroll
      for (int j = 0; j < 8; ++j) f[j] = (__bf16)Wd1[(kf * 32 + g * 8 + j) * 512 + col];
      bw1[cf][kf] = f;
    }
  }
  // Wd2 A-frags: frag[kf2] elem j = Wd2[kf2*32+g*8+j][wid*16+q]
  const int dimf = wid * 16 + q;
  bf16x8 bw2[16];
#pragma unroll
  for (int kf2 = 0; kf2 < 16; ++kf2) {
    bf16x8 f;
#pragma unroll
    for (int j = 0; j < 8; ++j) f[j] = (__bf16)Wd2[(kf2 * 32 + g * 8 + j) * 128 + dimf];
    bw2[kf2] = f;
  }
  f32x4 bd2v;
#pragma unroll
  for (int i = 0; i < 4; ++i) bd2v[i] = bd2[wid * 16 + g * 4 + i];

  const int srow = tid >> 4, sk8 = (tid & 15) * 8;
  const int stg_byte = ((srow * 256 + sk8 * 2) ^ ((srow & 7) << 4));
  char* hb = (char*)hbuf;

  float local = 0.f;

  // prologue
  {
    const float* p = z + (size_t)tile0 * 4096 + tid * 8;
    f32x4 r0 = *(const f32x4*)p, r1 = *(const f32x4*)(p + 4);
    bf16x8 v;
#pragma unroll
    for (int j = 0; j < 4; ++j) { v[j] = (__bf16)r0[j]; v[4 + j] = (__bf16)r1[j]; }
    *(bf16x8*)((char*)zbuf[0] + stg_byte) = v;
  }
  f32x4 rA0, rA1, rB0, rB1;
  { const float* p = z + (size_t)(tile0 + 1) * 4096 + tid * 8; rA0 = *(const f32x4*)p; rA1 = *(const f32x4*)(p + 4); }
  { const float* p = z + (size_t)(tile0 + 2) * 4096 + tid * 8; rB0 = *(const f32x4*)p; rB1 = *(const f32x4*)(p + 4); }
  __syncthreads();

#define DBODY(T, ZC, RR0, RR1)                                                     \
  do {                                                                             \
    f32x4 acc1[2][4] = {};                                                         \
    char* zc = (char*)zbuf[ZC];                                                    \
    _Pragma("unroll") for (int kf = 0; kf < 4; ++kf) {                             \
      _Pragma("unroll") for (int rf = 0; rf < 2; ++rf) {                           \
        const int row = rf * 16 + q;                                               \
        bf16x8 a = *(const bf16x8*)(zc + ((row * 256 + kf * 64 + g * 16) ^ ((row & 7) << 4))); \
        _Pragma("unroll") for (int cf = 0; cf < 4; ++cf)                           \
          acc1[rf][cf] = __builtin_amdgcn_mfma_f32_16x16x32_bf16(bw1[cf][kf], a, acc1[rf][cf], 0, 0, 0); \
      }                                                                            \
    }                                                                              \
    {                                                                              \
      bf16x8 v;                                                                    \
      _Pragma("unroll") for (int j = 0; j < 4; ++j) { v[j] = (__bf16)RR0[j]; v[4 + j] = (__bf16)RR1[j]; } \
      *(bf16x8*)((char*)zbuf[(ZC) ^ 1] + stg_byte) = v;                            \
    }                                                                              \
    {                                                                              \
      int tl = (T) + 3; if (tl > 7) tl = 7;                                        \
      const float* p = z + (size_t)(tile0 + tl) * 4096 + tid * 8;                  \
      RR0 = *(const f32x4*)p; RR1 = *(const f32x4*)(p + 4);                        \
    }                                                                              \
    /* h tile to LDS: packed 4x bf16 (consecutive hidden cols) */                  \
    _Pragma("unroll") for (int rf = 0; rf < 2; ++rf) {                             \
      const int row = rf * 16 + q;                                                 \
      _Pragma("unroll") for (int cf = 0; cf < 4; ++cf) {                           \
        bf16x4 hv;                                                                 \
        _Pragma("unroll") for (int i = 0; i < 4; ++i)                              \
          hv[i] = (__bf16)fmaxf(acc1[rf][cf][i] + bd1v[cf][i], 0.f);               \
        const int byt = ((row * 1024 + (cb + cf * 16 + g * 4) * 2) ^ ((row & 7) << 4)); \
        *(bf16x4*)(hb + byt) = hv;                                                 \
      }                                                                            \
    }                                                                              \
    __syncthreads(); /* h ready */                                                 \
    f32x4 acc2[2] = {};                                                            \
    _Pragma("unroll") for (int kf2 = 0; kf2 < 16; ++kf2) {                         \
      _Pragma("unroll") for (int rf2 = 0; rf2 < 2; ++rf2) {                        \
        const int row = rf2 * 16 + q;                                              \
        bf16x8 a = *(const bf16x8*)(hb + ((row * 1024 + kf2 * 64 + g * 16) ^ ((row & 7) << 4))); \
        acc2[rf2] = __builtin_amdgcn_mfma_f32_16x16x32_bf16(bw2[kf2], a, acc2[rf2], 0, 0, 0); \
      }                                                                            \
    }                                                                              \
    const int e = (tile0 + (T)) >> 1;                                              \
    _Pragma("unroll") for (int rf2 = 0; rf2 < 2; ++rf2) {                          \
      float partial = 0.f;                                                         \
      _Pragma("unroll") for (int i = 0; i < 4; ++i) {                              \
        const float xv = mp[e * 128 + wid * 16 + g * 4 + i];                       \
        const float d = xv - (acc2[rf2][i] + bd2v[i]);                             \
        partial += d * d;                                                          \
      }                                                                            \
      partial += __shfl_xor(partial, 16);                                          \
      partial += __shfl_xor(partial, 32);                                          \
      if (lid < 16) s_part[rf2 * 16 + lid][wid] = partial;                         \
    }                                                                              \
    __syncthreads();                                                               \
    if (tid < 32) {                                                                \
      float t2 = 0.f;                                                              \
      _Pragma("unroll") for (int w = 0; w < 8; ++w) t2 += s_part[tid][w];          \
      local += (-0.5f * t2 - 0.5f * 128.f * LOG_2PI) * (1.f / 64.f);               \
    }                                                                              \
  } while (0)

#pragma unroll 1
  for (int t = 0; t < 8; t += 2) {
    DBODY(t, 0, rA0, rA1);
    DBODY(t + 1, 1, rB0, rB1);
  }
#undef DBODY

  if (wid == 0) {
#pragma unroll
    for (int m = 16; m >= 1; m >>= 1) local += __shfl_xor(local, m);
    if (lid == 0) atomicAdd(recon_acc, local);
  }
}

// ---------------- finalize --------------------------------------------------
__global__ void finalize_kernel(const float* __restrict__ accs, float* __restrict__ out) {
  // accs: [0]=integral, [1]=log_intensity_sum, [2]=recon, [3]=sum(z_traj^2)
  const float kl = 0.01f * (accs[3] / 67108864.f);  // 8192*64*128
  const float elbo = accs[1] - accs[0] + accs[2] - kl;
  out[0] = -elbo;
}

extern "C" void kernel_launch(void* const* d_in, const int* in_sizes, int n_in,
                              void* d_out, int out_size, void* d_ws, size_t ws_size,
                              hipStream_t stream) {
  const float* event_marks = (const float*)d_in[0];
  const float* z_events = (const float*)d_in[1];
  const float* z_traj = (const float*)d_in[2];
  const float* times = (const float*)d_in[3];
  const float* Wp = (const float*)d_in[4];
  const float* bp = (const float*)d_in[5];
  const float* W1 = (const float*)d_in[6];
  const float* b1 = (const float*)d_in[7];
  const float* W2 = (const float*)d_in[8];
  const float* b2 = (const float*)d_in[9];
  const float* base_i = (const float*)d_in[10];
  const float* Wd1 = (const float*)d_in[11];
  const float* bd1 = (const float*)d_in[12];
  const float* Wd2 = (const float*)d_in[13];
  const float* bd2 = (const float*)d_in[14];

  float* mp = (float*)d_ws;                              // 1024*128 f32
  float* accs = (float*)((char*)d_ws + 1024 * 128 * 4);  // 4 f32 accumulators

  prep_kernel<<<1025, 128, 0, stream>>>(event_marks, Wp, bp, mp, accs);
  intensity2_kernel<<<1152, 512, 0, stream>>>(z_traj, z_events, W1, b1, W2, b2,
                                              base_i, times, accs);
  decoder2_kernel<<<256, 512, 0, stream>>>(z_events, Wd1, bd1, Wd2, bd2, mp,
                                           &accs[2]);
  finalize_kernel<<<1, 1, 0, stream>>>(accs, (float*)d_out);
}

// Round 4
// 192.523 us; speedup vs baseline: 2.1254x; 2.1254x over previous
//
#include <hip/hip_runtime.h>

typedef __attribute__((ext_vector_type(4))) float f32x4;
typedef __attribute__((ext_vector_type(8))) __bf16 bf16x8;
typedef __attribute__((ext_vector_type(4))) __bf16 bf16x4;

#define LOG_2PI 1.8378770664093453f

__device__ __forceinline__ float softplus_f(float x) {
  return fmaxf(x, 0.f) + log1pf(expf(-fabsf(x)));
}

// ---------------- prep: marks_proj (blocks 0..1023) + zero accs (block 1024)
__global__ void prep_kernel(const float* __restrict__ em,
                            const float* __restrict__ Wp,
                            const float* __restrict__ bp,
                            float* __restrict__ mp,
                            float* __restrict__ accs) {
  const int b = blockIdx.x;
  if (b == 1024) {
    if (threadIdx.x < 8) accs[threadIdx.x] = 0.f;
    return;
  }
  const int d = threadIdx.x;
  float s = bp[d];
  const float* emr = em + b * 128;
#pragma unroll 4
  for (int k = 0; k < 128; ++k) s += emr[k] * Wp[k * 128 + d];
  mp[b * 128 + d] = s;
}

// ---------------- fused intensity (traj blocks 0..1023, events 1024..1151) --
// Swapped MFMA: D[m=hidden][n=row]; in-register hidden reduction + 2 shuffles.
// 16 tiles/block, 2-deep named-register prefetch (issue t+3 in body t),
// 1 barrier/tile, deferred softplus via parity-buffered s_part.
__global__ __launch_bounds__(512, 2) void intensity3_kernel(
    const float* __restrict__ z_traj, const float* __restrict__ z_ev,
    const float* __restrict__ W1, const float* __restrict__ b1,
    const float* __restrict__ W2, const float* __restrict__ b2,
    const float* __restrict__ base_i, const float* __restrict__ times,
    float* __restrict__ accs) {
  __shared__ __align__(16) __bf16 zbuf[2][32 * 128];  // 16 KB
  __shared__ float s_part[2][32][9];
  __shared__ float red[8];
  __shared__ __align__(16) float b1L[512];
  __shared__ __align__(16) float w2L[512];

  const int tid = threadIdx.x;
  const int wid = tid >> 6, lid = tid & 63;
  const int g = lid >> 4, q = lid & 15;
  const int cb = wid * 64;

  const int b = blockIdx.x;
  const bool traj = (b < 1024);
  const float* z = traj ? z_traj : z_ev;
  const int tile0 = (traj ? b : (b - 1024)) * 16;

  b1L[tid] = b1[tid];
  w2L[tid] = W2[tid];

  // W1 A-frags: frag[cf][kf] elem j = W1[kf*32+g*8+j][cb+cf*16+q]
  bf16x8 bw[4][4];
#pragma unroll
  for (int cf = 0; cf < 4; ++cf) {
    const int col = cb + cf * 16 + q;
#pragma unroll
    for (int kf = 0; kf < 4; ++kf) {
      bf16x8 f;
#pragma unroll
      for (int j = 0; j < 8; ++j) f[j] = (__bf16)W1[(kf * 32 + g * 8 + j) * 512 + col];
      bw[cf][kf] = f;
    }
  }
  const float sbias = b2[0] + base_i[0];

  const int srow = tid >> 4, sk8 = (tid & 15) * 8;
  const int stg_byte = ((srow * 256 + sk8 * 2) ^ ((srow & 7) << 4));

  float local = 0.f, kls = 0.f;

  // prologue: stage tile0 into zbuf[0]; issue loads tile1->A, tile2->B
  {
    const float* p = z + (size_t)tile0 * 4096 + tid * 8;
    f32x4 r0 = *(const f32x4*)p, r1 = *(const f32x4*)(p + 4);
    if (traj) {
      kls += r0[0] * r0[0] + r0[1] * r0[1] + r0[2] * r0[2] + r0[3] * r0[3];
      kls += r1[0] * r1[0] + r1[1] * r1[1] + r1[2] * r1[2] + r1[3] * r1[3];
    }
    bf16x8 v;
#pragma unroll
    for (int j = 0; j < 4; ++j) { v[j] = (__bf16)r0[j]; v[4 + j] = (__bf16)r1[j]; }
    *(bf16x8*)((char*)zbuf[0] + stg_byte) = v;
  }
  f32x4 rA0, rA1, rB0, rB1;
  { const float* p = z + (size_t)(tile0 + 1) * 4096 + tid * 8; rA0 = *(const f32x4*)p; rA1 = *(const f32x4*)(p + 4); }
  { const float* p = z + (size_t)(tile0 + 2) * 4096 + tid * 8; rB0 = *(const f32x4*)p; rB1 = *(const f32x4*)(p + 4); }
  __syncthreads();

  // BODY(t): MFMA zbuf[t&1]; cvt slot (tile t+1) -> zbuf[(t+1)&1]; issue t+3;
  // epilogue -> s_part[t&1]; deferred finalize tile t-1; one barrier.
#define BODY(T, R0, R1, DO_STAGE, DO_ISSUE)                                        \
  do {                                                                             \
    f32x4 acc[2][4] = {};                                                          \
    char* zc = (char*)zbuf[(T) & 1];                                               \
    _Pragma("unroll") for (int kf = 0; kf < 4; ++kf) {                             \
      _Pragma("unroll") for (int rf = 0; rf < 2; ++rf) {                           \
        const int row = rf * 16 + q;                                               \
        bf16x8 a = *(const bf16x8*)(zc + ((row * 256 + kf * 64 + g * 16) ^ ((row & 7) << 4))); \
        _Pragma("unroll") for (int cf = 0; cf < 4; ++cf)                           \
          acc[rf][cf] = __builtin_amdgcn_mfma_f32_16x16x32_bf16(bw[cf][kf], a, acc[rf][cf], 0, 0, 0); \
      }                                                                            \
    }                                                                              \
    if (DO_STAGE) {                                                                \
      if (traj) {                                                                  \
        kls += R0[0] * R0[0] + R0[1] * R0[1] + R0[2] * R0[2] + R0[3] * R0[3];      \
        kls += R1[0] * R1[0] + R1[1] * R1[1] + R1[2] * R1[2] + R1[3] * R1[3];      \
      }                                                                            \
      bf16x8 v;                                                                    \
      _Pragma("unroll") for (int j = 0; j < 4; ++j) { v[j] = (__bf16)R0[j]; v[4 + j] = (__bf16)R1[j]; } \
      *(bf16x8*)((char*)zbuf[((T) + 1) & 1] + stg_byte) = v;                       \
      if (DO_ISSUE) {                                                              \
        const float* p = z + (size_t)(tile0 + (T) + 3) * 4096 + tid * 8;           \
        R0 = *(const f32x4*)p; R1 = *(const f32x4*)(p + 4);                        \
      }                                                                            \
    }                                                                              \
    _Pragma("unroll") for (int rf = 0; rf < 2; ++rf) {                             \
      float partial = 0.f;                                                         \
      _Pragma("unroll") for (int cf = 0; cf < 4; ++cf) {                           \
        const int c0 = cb + cf * 16 + g * 4;                                       \
        f32x4 bv = *(const f32x4*)&b1L[c0];                                        \
        f32x4 wv = *(const f32x4*)&w2L[c0];                                        \
        _Pragma("unroll") for (int i = 0; i < 4; ++i)                              \
          partial += fmaxf(acc[rf][cf][i] + bv[i], 0.f) * wv[i];                   \
      }                                                                            \
      partial += __shfl_xor(partial, 16);                                          \
      partial += __shfl_xor(partial, 32);                                          \
      if (lid < 16) s_part[(T) & 1][rf * 16 + lid][wid] = partial;                 \
    }                                                                              \
    if ((T) > 0 && tid < 32) {                                                     \
      float s = sbias;                                                             \
      _Pragma("unroll") for (int w = 0; w < 8; ++w) s += s_part[((T) + 1) & 1][tid][w]; \
      const float lam = softplus_f(s);                                             \
      const int ta = tile0 + (T) - 1;                                              \
      if (traj) {                                                                  \
        const int ts = ta >> 1;                                                    \
        local += lam * (times[ts + 1] - times[ts]) * (1.f / 64.f);                 \
      } else {                                                                     \
        local += logf(lam + 1e-8f) * (1.f / 64.f);                                 \
      }                                                                            \
    }                                                                              \
    __syncthreads();                                                               \
  } while (0)

  int t = 0;
#pragma unroll 1
  for (int it = 0; it < 7; ++it) {  // t = 0..13
    BODY(t, rA0, rA1, true, (t + 3 <= 15)); ++t;
    BODY(t, rB0, rB1, true, (t + 3 <= 15)); ++t;
  }
  BODY(t, rA0, rA1, true, false); ++t;  // t=14: stages tile15 (slot A holds it)
  BODY(t, rB0, rB1, false, false);      // t=15: compute only
#undef BODY

  // tail: finalize tile 15 (s_part[15&1 = 1])
  if (tid < 32) {
    float s = sbias;
#pragma unroll
    for (int w = 0; w < 8; ++w) s += s_part[1][tid][w];
    const float lam = softplus_f(s);
    const int ta = tile0 + 15;
    if (traj) {
      const int ts = ta >> 1;
      local += lam * (times[ts + 1] - times[ts]) * (1.f / 64.f);
    } else {
      local += logf(lam + 1e-8f) * (1.f / 64.f);
    }
  }

  // block reductions + atomics (local lives on wave 0, lanes 0..31)
  if (wid == 0) {
#pragma unroll
    for (int m = 16; m >= 1; m >>= 1) local += __shfl_xor(local, m);
    if (lid == 0) atomicAdd(traj ? &accs[0] : &accs[1], local);
  }
  if (traj) {
#pragma unroll
    for (int m = 32; m >= 1; m >>= 1) kls += __shfl_xor(kls, m);
    if (lid == 0) red[wid] = kls;
    __syncthreads();
    if (tid == 0) {
      float s = 0.f;
      for (int w = 0; w < 8; ++w) s += red[w];
      atomicAdd(&accs[3], s);
    }
  }
}

// ---------------- decoder: swapped GEMM1 -> h (LDS) -> swapped GEMM2 -> logp
__global__ __launch_bounds__(512, 2) void decoder2_kernel(
    const float* __restrict__ z,
    const float* __restrict__ Wd1, const float* __restrict__ bd1,
    const float* __restrict__ Wd2, const float* __restrict__ bd2,
    const float* __restrict__ mp, float* __restrict__ recon_acc) {
  __shared__ __align__(16) __bf16 zbuf[2][32 * 128];  // 16 KB
  __shared__ __align__(16) __bf16 hbuf[32 * 512];     // 32 KB
  __shared__ float s_part[32][9];
  __shared__ float red[8];

  const int tid = threadIdx.x;
  const int wid = tid >> 6, lid = tid & 63;
  const int g = lid >> 4, q = lid & 15;
  const int cb = wid * 64;
  const int tile0 = blockIdx.x * 8;

  bf16x8 bw1[4][4];
  f32x4 bd1v[4];
#pragma unroll
  for (int cf = 0; cf < 4; ++cf) {
    const int col = cb + cf * 16 + q;
#pragma unroll
    for (int i = 0; i < 4; ++i) bd1v[cf][i] = bd1[cb + cf * 16 + g * 4 + i];
#pragma unroll
    for (int kf = 0; kf < 4; ++kf) {
      bf16x8 f;
#pragma unroll
      for (int j = 0; j < 8; ++j) f[j] = (__bf16)Wd1[(kf * 32 + g * 8 + j) * 512 + col];
      bw1[cf][kf] = f;
    }
  }
  const int dimf = wid * 16 + q;
  bf16x8 bw2[16];
#pragma unroll
  for (int kf2 = 0; kf2 < 16; ++kf2) {
    bf16x8 f;
#pragma unroll
    for (int j = 0; j < 8; ++j) f[j] = (__bf16)Wd2[(kf2 * 32 + g * 8 + j) * 128 + dimf];
    bw2[kf2] = f;
  }
  f32x4 bd2v;
#pragma unroll
  for (int i = 0; i < 4; ++i) bd2v[i] = bd2[wid * 16 + g * 4 + i];

  const int srow = tid >> 4, sk8 = (tid & 15) * 8;
  const int stg_byte = ((srow * 256 + sk8 * 2) ^ ((srow & 7) << 4));
  char* hb = (char*)hbuf;

  float local = 0.f;

  {
    const float* p = z + (size_t)tile0 * 4096 + tid * 8;
    f32x4 r0 = *(const f32x4*)p, r1 = *(const f32x4*)(p + 4);
    bf16x8 v;
#pragma unroll
    for (int j = 0; j < 4; ++j) { v[j] = (__bf16)r0[j]; v[4 + j] = (__bf16)r1[j]; }
    *(bf16x8*)((char*)zbuf[0] + stg_byte) = v;
  }
  f32x4 rA0, rA1, rB0, rB1;
  { const float* p = z + (size_t)(tile0 + 1) * 4096 + tid * 8; rA0 = *(const f32x4*)p; rA1 = *(const f32x4*)(p + 4); }
  { const float* p = z + (size_t)(tile0 + 2) * 4096 + tid * 8; rB0 = *(const f32x4*)p; rB1 = *(const f32x4*)(p + 4); }
  __syncthreads();

#define DBODY(T, ZC, RR0, RR1)                                                     \
  do {                                                                             \
    f32x4 acc1[2][4] = {};                                                         \
    char* zc = (char*)zbuf[ZC];                                                    \
    _Pragma("unroll") for (int kf = 0; kf < 4; ++kf) {                             \
      _Pragma("unroll") for (int rf = 0; rf < 2; ++rf) {                           \
        const int row = rf * 16 + q;                                               \
        bf16x8 a = *(const bf16x8*)(zc + ((row * 256 + kf * 64 + g * 16) ^ ((row & 7) << 4))); \
        _Pragma("unroll") for (int cf = 0; cf < 4; ++cf)                           \
          acc1[rf][cf] = __builtin_amdgcn_mfma_f32_16x16x32_bf16(bw1[cf][kf], a, acc1[rf][cf], 0, 0, 0); \
      }                                                                            \
    }                                                                              \
    {                                                                              \
      bf16x8 v;                                                                    \
      _Pragma("unroll") for (int j = 0; j < 4; ++j) { v[j] = (__bf16)RR0[j]; v[4 + j] = (__bf16)RR1[j]; } \
      *(bf16x8*)((char*)zbuf[(ZC) ^ 1] + stg_byte) = v;                            \
    }                                                                              \
    {                                                                              \
      int tl = (T) + 3; if (tl > 7) tl = 7;                                        \
      const float* p = z + (size_t)(tile0 + tl) * 4096 + tid * 8;                  \
      RR0 = *(const f32x4*)p; RR1 = *(const f32x4*)(p + 4);                        \
    }                                                                              \
    _Pragma("unroll") for (int rf = 0; rf < 2; ++rf) {                             \
      const int row = rf * 16 + q;                                                 \
      _Pragma("unroll") for (int cf = 0; cf < 4; ++cf) {                           \
        bf16x4 hv;                                                                 \
        _Pragma("unroll") for (int i = 0; i < 4; ++i)                              \
          hv[i] = (__bf16)fmaxf(acc1[rf][cf][i] + bd1v[cf][i], 0.f);               \
        const int byt = ((row * 1024 + (cb + cf * 16 + g * 4) * 2) ^ ((row & 7) << 4)); \
        *(bf16x4*)(hb + byt) = hv;                                                 \
      }                                                                            \
    }                                                                              \
    __syncthreads();                                                               \
    f32x4 acc2[2] = {};                                                            \
    _Pragma("unroll") for (int kf2 = 0; kf2 < 16; ++kf2) {                         \
      _Pragma("unroll") for (int rf2 = 0; rf2 < 2; ++rf2) {                        \
        const int row = rf2 * 16 + q;                                              \
        bf16x8 a = *(const bf16x8*)(hb + ((row * 1024 + kf2 * 64 + g * 16) ^ ((row & 7) << 4))); \
        acc2[rf2] = __builtin_amdgcn_mfma_f32_16x16x32_bf16(bw2[kf2], a, acc2[rf2], 0, 0, 0); \
      }                                                                            \
    }                                                                              \
    const int e = (tile0 + (T)) >> 1;                                              \
    _Pragma("unroll") for (int rf2 = 0; rf2 < 2; ++rf2) {                          \
      float partial = 0.f;                                                         \
      _Pragma("unroll") for (int i = 0; i < 4; ++i) {                              \
        const float xv = mp[e * 128 + wid * 16 + g * 4 + i];                       \
        const float d = xv - (acc2[rf2][i] + bd2v[i]);                             \
        partial += d * d;                                                          \
      }                                                                            \
      partial += __shfl_xor(partial, 16);                                          \
      partial += __shfl_xor(partial, 32);                                          \
      if (lid < 16) s_part[rf2 * 16 + lid][wid] = partial;                         \
    }                                                                              \
    __syncthreads();                                                               \
    if (tid < 32) {                                                                \
      float t2 = 0.f;                                                              \
      _Pragma("unroll") for (int w = 0; w < 8; ++w) t2 += s_part[tid][w];          \
      local += (-0.5f * t2 - 0.5f * 128.f * LOG_2PI) * (1.f / 64.f);               \
    }                                                                              \
  } while (0)

#pragma unroll 1
  for (int t = 0; t < 8; t += 2) {
    DBODY(t, 0, rA0, rA1);
    DBODY(t + 1, 1, rB0, rB1);
  }
#undef DBODY

  if (wid == 0) {
#pragma unroll
    for (int m = 16; m >= 1; m >>= 1) local += __shfl_xor(local, m);
    if (lid == 0) atomicAdd(recon_acc, local);
  }
}

// ---------------- finalize --------------------------------------------------
__global__ void finalize_kernel(const float* __restrict__ accs, float* __restrict__ out) {
  // accs: [0]=integral, [1]=log_intensity_sum, [2]=recon, [3]=sum(z_traj^2)
  const float kl = 0.01f * (accs[3] / 67108864.f);  // 8192*64*128
  const float elbo = accs[1] - accs[0] + accs[2] - kl;
  out[0] = -elbo;
}

extern "C" void kernel_launch(void* const* d_in, const int* in_sizes, int n_in,
                              void* d_out, int out_size, void* d_ws, size_t ws_size,
                              hipStream_t stream) {
  const float* event_marks = (const float*)d_in[0];
  const float* z_events = (const float*)d_in[1];
  const float* z_traj = (const float*)d_in[2];
  const float* times = (const float*)d_in[3];
  const float* Wp = (const float*)d_in[4];
  const float* bp = (const float*)d_in[5];
  const float* W1 = (const float*)d_in[6];
  const float* b1 = (const float*)d_in[7];
  const float* W2 = (const float*)d_in[8];
  const float* b2 = (const float*)d_in[9];
  const float* base_i = (const float*)d_in[10];
  const float* Wd1 = (const float*)d_in[11];
  const float* bd1 = (const float*)d_in[12];
  const float* Wd2 = (const float*)d_in[13];
  const float* bd2 = (const float*)d_in[14];

  float* mp = (float*)d_ws;                              // 1024*128 f32
  float* accs = (float*)((char*)d_ws + 1024 * 128 * 4);  // 4 f32 accumulators

  prep_kernel<<<1025, 128, 0, stream>>>(event_marks, Wp, bp, mp, accs);
  intensity3_kernel<<<1152, 512, 0, stream>>>(z_traj, z_events, W1, b1, W2, b2,
                                              base_i, times, accs);
  decoder2_kernel<<<256, 512, 0, stream>>>(z_events, Wd1, bd1, Wd2, bd2, mp,
                                           &accs[2]);
  finalize_kernel<<<1, 1, 0, stream>>>(accs, (float*)d_out);
}

// Round 5
// 175.157 us; speedup vs baseline: 2.3361x; 1.0991x over previous
//
#include <hip/hip_runtime.h>

typedef __attribute__((ext_vector_type(4))) float f32x4;
typedef __attribute__((ext_vector_type(8))) __bf16 bf16x8;
typedef __attribute__((ext_vector_type(4))) __bf16 bf16x4;

#define LOG_2PI 1.8378770664093453f

__device__ __forceinline__ float softplus_f(float x) {
  return fmaxf(x, 0.f) + log1pf(expf(-fabsf(x)));
}

// ---------------- prep: marks_proj (blocks 0..1023) + zero accs (block 1024)
__global__ void prep_kernel(const float* __restrict__ em,
                            const float* __restrict__ Wp,
                            const float* __restrict__ bp,
                            float* __restrict__ mp,
                            float* __restrict__ accs) {
  const int b = blockIdx.x;
  if (b == 1024) {
    if (threadIdx.x < 8) accs[threadIdx.x] = 0.f;
    return;
  }
  const int d = threadIdx.x;
  float s = bp[d];
  const float* emr = em + b * 128;
#pragma unroll 4
  for (int k = 0; k < 128; ++k) s += emr[k] * Wp[k * 128 + d];
  mp[b * 128 + d] = s;
}

// ---------------- fused intensity (traj blocks 0..1023, events 1024..1151) --
// Swapped MFMA: D[m=hidden][n=row]. Per-tile: MFMA + epilogue -> s_part[tile],
// ONE barrier (zbuf handoff only). Batched finalize after the 16-tile loop:
// 512 threads each own one (tile,row) -> softplus in parallel, no serial section.
__global__ __launch_bounds__(512, 2) void intensity4_kernel(
    const float* __restrict__ z_traj, const float* __restrict__ z_ev,
    const float* __restrict__ W1, const float* __restrict__ b1,
    const float* __restrict__ W2, const float* __restrict__ b2,
    const float* __restrict__ base_i, const float* __restrict__ times,
    float* __restrict__ accs) {
  __shared__ __align__(16) __bf16 zbuf[2][32 * 128];  // 16 KB
  __shared__ float s_part[16][32][9];                 // 18.4 KB, padded
  __shared__ float red[8];

  const int tid = threadIdx.x;
  const int wid = tid >> 6, lid = tid & 63;
  const int g = lid >> 4, q = lid & 15;
  const int cb = wid * 64;

  const int b = blockIdx.x;
  const bool traj = (b < 1024);
  const float* z = traj ? z_traj : z_ev;
  const int tile0 = (traj ? b : (b - 1024)) * 16;

  // W1 A-frags: frag[cf][kf] elem j = W1[kf*32+g*8+j][cb+cf*16+q]
  bf16x8 bw[4][4];
#pragma unroll
  for (int cf = 0; cf < 4; ++cf) {
    const int col = cb + cf * 16 + q;
#pragma unroll
    for (int kf = 0; kf < 4; ++kf) {
      bf16x8 f;
#pragma unroll
      for (int j = 0; j < 8; ++j) f[j] = (__bf16)W1[(kf * 32 + g * 8 + j) * 512 + col];
      bw[cf][kf] = f;
    }
  }
  // b1/W2 for this lane's 16 hidden cols, in registers (vector loads)
  f32x4 bv[4], wv[4];
#pragma unroll
  for (int cf = 0; cf < 4; ++cf) {
    const int c0 = cb + cf * 16 + g * 4;
    bv[cf] = *(const f32x4*)&b1[c0];
    wv[cf] = *(const f32x4*)&W2[c0];
  }
  const float sbias = b2[0] + base_i[0];

  const int srow = tid >> 4, sk8 = (tid & 15) * 8;
  const int stg_byte = ((srow * 256 + sk8 * 2) ^ ((srow & 7) << 4));

  float kls = 0.f;

  // prologue: stage tile0 into zbuf[0]; issue loads tile1->A, tile2->B
  {
    const float* p = z + (size_t)tile0 * 4096 + tid * 8;
    f32x4 r0 = *(const f32x4*)p, r1 = *(const f32x4*)(p + 4);
    if (traj) {
      kls += r0[0] * r0[0] + r0[1] * r0[1] + r0[2] * r0[2] + r0[3] * r0[3];
      kls += r1[0] * r1[0] + r1[1] * r1[1] + r1[2] * r1[2] + r1[3] * r1[3];
    }
    bf16x8 v;
#pragma unroll
    for (int j = 0; j < 4; ++j) { v[j] = (__bf16)r0[j]; v[4 + j] = (__bf16)r1[j]; }
    *(bf16x8*)((char*)zbuf[0] + stg_byte) = v;
  }
  f32x4 rA0, rA1, rB0, rB1;
  { const float* p = z + (size_t)(tile0 + 1) * 4096 + tid * 8; rA0 = *(const f32x4*)p; rA1 = *(const f32x4*)(p + 4); }
  { const float* p = z + (size_t)(tile0 + 2) * 4096 + tid * 8; rB0 = *(const f32x4*)p; rB1 = *(const f32x4*)(p + 4); }
  __syncthreads();

  // BODY(t): MFMA zbuf[t&1]; cvt slot (tile t+1) -> zbuf[(t+1)&1]; issue t+3;
  // epilogue -> s_part[t]; ONE barrier.
#define BODY(T, R0, R1, DO_STAGE, DO_ISSUE)                                        \
  do {                                                                             \
    f32x4 acc[2][4] = {};                                                          \
    char* zc = (char*)zbuf[(T) & 1];                                               \
    _Pragma("unroll") for (int kf = 0; kf < 4; ++kf) {                             \
      _Pragma("unroll") for (int rf = 0; rf < 2; ++rf) {                           \
        const int row = rf * 16 + q;                                               \
        bf16x8 a = *(const bf16x8*)(zc + ((row * 256 + kf * 64 + g * 16) ^ ((row & 7) << 4))); \
        _Pragma("unroll") for (int cf = 0; cf < 4; ++cf)                           \
          acc[rf][cf] = __builtin_amdgcn_mfma_f32_16x16x32_bf16(bw[cf][kf], a, acc[rf][cf], 0, 0, 0); \
      }                                                                            \
    }                                                                              \
    if (DO_STAGE) {                                                                \
      if (traj) {                                                                  \
        kls += R0[0] * R0[0] + R0[1] * R0[1] + R0[2] * R0[2] + R0[3] * R0[3];      \
        kls += R1[0] * R1[0] + R1[1] * R1[1] + R1[2] * R1[2] + R1[3] * R1[3];      \
      }                                                                            \
      bf16x8 v;                                                                    \
      _Pragma("unroll") for (int j = 0; j < 4; ++j) { v[j] = (__bf16)R0[j]; v[4 + j] = (__bf16)R1[j]; } \
      *(bf16x8*)((char*)zbuf[((T) + 1) & 1] + stg_byte) = v;                       \
      if (DO_ISSUE) {                                                              \
        const float* p = z + (size_t)(tile0 + (T) + 3) * 4096 + tid * 8;           \
        R0 = *(const f32x4*)p; R1 = *(const f32x4*)(p + 4);                        \
      }                                                                            \
    }                                                                              \
    _Pragma("unroll") for (int rf = 0; rf < 2; ++rf) {                             \
      float partial = 0.f;                                                         \
      _Pragma("unroll") for (int cf = 0; cf < 4; ++cf) {                           \
        _Pragma("unroll") for (int i = 0; i < 4; ++i)                              \
          partial += fmaxf(acc[rf][cf][i] + bv[cf][i], 0.f) * wv[cf][i];           \
      }                                                                            \
      partial += __shfl_xor(partial, 16);                                          \
      partial += __shfl_xor(partial, 32);                                          \
      if (lid < 16) s_part[(T)][rf * 16 + lid][wid] = partial;                     \
    }                                                                              \
    __syncthreads();                                                               \
  } while (0)

  int t = 0;
#pragma unroll 1
  for (int it = 0; it < 7; ++it) {  // t = 0..13
    BODY(t, rA0, rA1, true, (t + 3 <= 15)); ++t;
    BODY(t, rB0, rB1, true, (t + 3 <= 15)); ++t;
  }
  BODY(t, rA0, rA1, true, false); ++t;  // t=14: stages tile15
  BODY(t, rB0, rB1, false, false);      // t=15: compute only
#undef BODY

  // ---- batched finalize: 512 threads, one (tile,row) each ----
  float local;
  {
    const int tt = tid >> 5, r = tid & 31;
    float s = sbias;
#pragma unroll
    for (int w = 0; w < 8; ++w) s += s_part[tt][r][w];
    const float lam = softplus_f(s);
    if (traj) {
      const int R = (tile0 + tt) * 32 + r;
      const int ts = R >> 6;
      local = lam * (times[ts + 1] - times[ts]) * (1.f / 64.f);
    } else {
      local = logf(lam + 1e-8f) * (1.f / 64.f);
    }
  }
#pragma unroll
  for (int m = 32; m >= 1; m >>= 1) local += __shfl_xor(local, m);
  if (lid == 0) red[wid] = local;
  __syncthreads();
  if (tid == 0) {
    float s = 0.f;
#pragma unroll
    for (int w = 0; w < 8; ++w) s += red[w];
    atomicAdd(traj ? &accs[0] : &accs[1], s);
  }
  if (traj) {
    __syncthreads();
#pragma unroll
    for (int m = 32; m >= 1; m >>= 1) kls += __shfl_xor(kls, m);
    if (lid == 0) red[wid] = kls;
    __syncthreads();
    if (tid == 0) {
      float s = 0.f;
#pragma unroll
      for (int w = 0; w < 8; ++w) s += red[w];
      atomicAdd(&accs[3], s);
    }
  }
}

// ---------------- decoder: swapped GEMM1 -> h (LDS) -> swapped GEMM2 -> logp
__global__ __launch_bounds__(512, 2) void decoder2_kernel(
    const float* __restrict__ z,
    const float* __restrict__ Wd1, const float* __restrict__ bd1,
    const float* __restrict__ Wd2, const float* __restrict__ bd2,
    const float* __restrict__ mp, float* __restrict__ recon_acc) {
  __shared__ __align__(16) __bf16 zbuf[2][32 * 128];  // 16 KB
  __shared__ __align__(16) __bf16 hbuf[32 * 512];     // 32 KB
  __shared__ float s_part[32][9];
  __shared__ float red[8];

  const int tid = threadIdx.x;
  const int wid = tid >> 6, lid = tid & 63;
  const int g = lid >> 4, q = lid & 15;
  const int cb = wid * 64;
  const int tile0 = blockIdx.x * 8;

  bf16x8 bw1[4][4];
  f32x4 bd1v[4];
#pragma unroll
  for (int cf = 0; cf < 4; ++cf) {
    const int col = cb + cf * 16 + q;
#pragma unroll
    for (int i = 0; i < 4; ++i) bd1v[cf][i] = bd1[cb + cf * 16 + g * 4 + i];
#pragma unroll
    for (int kf = 0; kf < 4; ++kf) {
      bf16x8 f;
#pragma unroll
      for (int j = 0; j < 8; ++j) f[j] = (__bf16)Wd1[(kf * 32 + g * 8 + j) * 512 + col];
      bw1[cf][kf] = f;
    }
  }
  const int dimf = wid * 16 + q;
  bf16x8 bw2[16];
#pragma unroll
  for (int kf2 = 0; kf2 < 16; ++kf2) {
    bf16x8 f;
#pragma unroll
    for (int j = 0; j < 8; ++j) f[j] = (__bf16)Wd2[(kf2 * 32 + g * 8 + j) * 128 + dimf];
    bw2[kf2] = f;
  }
  f32x4 bd2v;
#pragma unroll
  for (int i = 0; i < 4; ++i) bd2v[i] = bd2[wid * 16 + g * 4 + i];

  const int srow = tid >> 4, sk8 = (tid & 15) * 8;
  const int stg_byte = ((srow * 256 + sk8 * 2) ^ ((srow & 7) << 4));
  char* hb = (char*)hbuf;

  float local = 0.f;

  {
    const float* p = z + (size_t)tile0 * 4096 + tid * 8;
    f32x4 r0 = *(const f32x4*)p, r1 = *(const f32x4*)(p + 4);
    bf16x8 v;
#pragma unroll
    for (int j = 0; j < 4; ++j) { v[j] = (__bf16)r0[j]; v[4 + j] = (__bf16)r1[j]; }
    *(bf16x8*)((char*)zbuf[0] + stg_byte) = v;
  }
  f32x4 rA0, rA1, rB0, rB1;
  { const float* p = z + (size_t)(tile0 + 1) * 4096 + tid * 8; rA0 = *(const f32x4*)p; rA1 = *(const f32x4*)(p + 4); }
  { const float* p = z + (size_t)(tile0 + 2) * 4096 + tid * 8; rB0 = *(const f32x4*)p; rB1 = *(const f32x4*)(p + 4); }
  __syncthreads();

#define DBODY(T, ZC, RR0, RR1)                                                     \
  do {                                                                             \
    f32x4 acc1[2][4] = {};                                                         \
    char* zc = (char*)zbuf[ZC];                                                    \
    _Pragma("unroll") for (int kf = 0; kf < 4; ++kf) {                             \
      _Pragma("unroll") for (int rf = 0; rf < 2; ++rf) {                           \
        const int row = rf * 16 + q;                                               \
        bf16x8 a = *(const bf16x8*)(zc + ((row * 256 + kf * 64 + g * 16) ^ ((row & 7) << 4))); \
        _Pragma("unroll") for (int cf = 0; cf < 4; ++cf)                           \
          acc1[rf][cf] = __builtin_amdgcn_mfma_f32_16x16x32_bf16(bw1[cf][kf], a, acc1[rf][cf], 0, 0, 0); \
      }                                                                            \
    }                                                                              \
    {                                                                              \
      bf16x8 v;                                                                    \
      _Pragma("unroll") for (int j = 0; j < 4; ++j) { v[j] = (__bf16)RR0[j]; v[4 + j] = (__bf16)RR1[j]; } \
      *(bf16x8*)((char*)zbuf[(ZC) ^ 1] + stg_byte) = v;                            \
    }                                                                              \
    {                                                                              \
      int tl = (T) + 3; if (tl > 7) tl = 7;                                        \
      const float* p = z + (size_t)(tile0 + tl) * 4096 + tid * 8;                  \
      RR0 = *(const f32x4*)p; RR1 = *(const f32x4*)(p + 4);                        \
    }                                                                              \
    _Pragma("unroll") for (int rf = 0; rf < 2; ++rf) {                             \
      const int row = rf * 16 + q;                                                 \
      _Pragma("unroll") for (int cf = 0; cf < 4; ++cf) {                           \
        bf16x4 hv;                                                                 \
        _Pragma("unroll") for (int i = 0; i < 4; ++i)                              \
          hv[i] = (__bf16)fmaxf(acc1[rf][cf][i] + bd1v[cf][i], 0.f);               \
        const int byt = ((row * 1024 + (cb + cf * 16 + g * 4) * 2) ^ ((row & 7) << 4)); \
        *(bf16x4*)(hb + byt) = hv;                                                 \
      }                                                                            \
    }                                                                              \
    __syncthreads();                                                               \
    f32x4 acc2[2] = {};                                                            \
    _Pragma("unroll") for (int kf2 = 0; kf2 < 16; ++kf2) {                         \
      _Pragma("unroll") for (int rf2 = 0; rf2 < 2; ++rf2) {                        \
        const int row = rf2 * 16 + q;                                              \
        bf16x8 a = *(const bf16x8*)(hb + ((row * 1024 + kf2 * 64 + g * 16) ^ ((row & 7) << 4))); \
        acc2[rf2] = __builtin_amdgcn_mfma_f32_16x16x32_bf16(bw2[kf2], a, acc2[rf2], 0, 0, 0); \
      }                                                                            \
    }                                                                              \
    const int e = (tile0 + (T)) >> 1;                                              \
    _Pragma("unroll") for (int rf2 = 0; rf2 < 2; ++rf2) {                          \
      float partial = 0.f;                                                         \
      _Pragma("unroll") for (int i = 0; i < 4; ++i) {                              \
        const float xv = mp[e * 128 + wid * 16 + g * 4 + i];                       \
        const float d = xv - (acc2[rf2][i] + bd2v[i]);                             \
        partial += d * d;                                                          \
      }                                                                            \
      partial += __shfl_xor(partial, 16);                                          \
      partial += __shfl_xor(partial, 32);                                          \
      if (lid < 16) s_part[rf2 * 16 + lid][wid] = partial;                         \
    }                                                                              \
    __syncthreads();                                                               \
    if (tid < 32) {                                                                \
      float t2 = 0.f;                                                              \
      _Pragma("unroll") for (int w = 0; w < 8; ++w) t2 += s_part[tid][w];          \
      local += (-0.5f * t2 - 0.5f * 128.f * LOG_2PI) * (1.f / 64.f);               \
    }                                                                              \
  } while (0)

#pragma unroll 1
  for (int t = 0; t < 8; t += 2) {
    DBODY(t, 0, rA0, rA1);
    DBODY(t + 1, 1, rB0, rB1);
  }
#undef DBODY

  if (wid == 0) {
#pragma unroll
    for (int m = 16; m >= 1; m >>= 1) local += __shfl_xor(local, m);
    if (lid == 0) atomicAdd(recon_acc, local);
  }
}

// ---------------- finalize --------------------------------------------------
__global__ void finalize_kernel(const float* __restrict__ accs, float* __restrict__ out) {
  // accs: [0]=integral, [1]=log_intensity_sum, [2]=recon, [3]=sum(z_traj^2)
  const float kl = 0.01f * (accs[3] / 67108864.f);  // 8192*64*128
  const float elbo = accs[1] - accs[0] + accs[2] - kl;
  out[0] = -elbo;
}

extern "C" void kernel_launch(void* const* d_in, const int* in_sizes, int n_in,
                              void* d_out, int out_size, void* d_ws, size_t ws_size,
                              hipStream_t stream) {
  const float* event_marks = (const float*)d_in[0];
  const float* z_events = (const float*)d_in[1];
  const float* z_traj = (const float*)d_in[2];
  const float* times = (const float*)d_in[3];
  const float* Wp = (const float*)d_in[4];
  const float* bp = (const float*)d_in[5];
  const float* W1 = (const float*)d_in[6];
  const float* b1 = (const float*)d_in[7];
  const float* W2 = (const float*)d_in[8];
  const float* b2 = (const float*)d_in[9];
  const float* base_i = (const float*)d_in[10];
  const float* Wd1 = (const float*)d_in[11];
  const float* bd1 = (const float*)d_in[12];
  const float* Wd2 = (const float*)d_in[13];
  const float* bd2 = (const float*)d_in[14];

  float* mp = (float*)d_ws;                              // 1024*128 f32
  float* accs = (float*)((char*)d_ws + 1024 * 128 * 4);  // 4 f32 accumulators

  prep_kernel<<<1025, 128, 0, stream>>>(event_marks, Wp, bp, mp, accs);
  intensity4_kernel<<<1152, 512, 0, stream>>>(z_traj, z_events, W1, b1, W2, b2,
                                              base_i, times, accs);
  decoder2_kernel<<<256, 512, 0, stream>>>(z_events, Wd1, bd1, Wd2, bd2, mp,
                                           &accs[2]);
  finalize_kernel<<<1, 1, 0, stream>>>(accs, (float*)d_out);
}